// Round 3
// baseline (303.293 us; speedup 1.0000x reference)
//
#include <hip/hip_runtime.h>
#include <hip/hip_fp16.h>

// GCN 2-layer: out = D_in^-1/2 A D_out^-1/2 (relu(D_in^-1/2 A D_out^-1/2 X W1 + b1)) W2 + b2
// Strategy: project-then-aggregate; CSR-by-dst via radix partition.
// R7: radix-partition CSR 368us. R8: dual partition 354us.
// R9 FAILED (1604us): LDS fp32 atomicAdd aggregate -> CAS serialization.
// R10: half-wave/node aggregate, clamped unroll-8 (every row 8 gathers in
//      flight). 302us; agg ~38us, gemm<128> now top at 50us (VALU-bound).
// R11: (a) MFMA GEMM — hi/lo fp16 split (3x mfma_f32_16x16x32_f16, fp32 acc;
//      error ~2^-22, no accuracy change) with LDS-transposed padded W.
//      (b) delete src-side partition; cnt_out = fire-and-forget global
//      atomics in part_hist (+memset). No rank-returning atomics anywhere.

static inline size_t align256(size_t x) { return (x + 255) & ~(size_t)255; }

#define BKT_SHIFT 7
#define BKT_W 128              // nodes per bucket window
#define MAX_NBK 800            // LDS sizing guard (N <= 102400)
#define PA_BLOCKS 416          // partition pass blocks

typedef _Float16 f16x8 __attribute__((ext_vector_type(8)));
typedef float f32x4 __attribute__((ext_vector_type(4)));

// A1: per-block bucket histogram of dst>>7; out-degree via global atomics.
__global__ __launch_bounds__(256)
void part_hist_kernel(const int* __restrict__ src, const int* __restrict__ dst,
                      int* __restrict__ hist_d, int* __restrict__ cnt_out,
                      int nbk, int E, int slice_len) {
    __shared__ int hd[MAX_NBK];
    const int b = blockIdx.x;
    for (int i = threadIdx.x; i < nbk; i += 256) hd[i] = 0;
    __syncthreads();
    const int beg = b * slice_len;
    const int end = min(beg + slice_len, E);
    for (int i = beg + threadIdx.x; i < end; i += 256) {
        atomicAdd(&hd[dst[i] >> BKT_SHIFT], 1);   // LDS atomic (int: native)
        atomicAdd(&cnt_out[src[i]], 1);           // fire-and-forget global
    }
    __syncthreads();
    for (int i = threadIdx.x; i < nbk; i += 256)
        hist_d[(size_t)i * PA_BLOCKS + b] = hd[i];
}

// A2: per-bucket-row exclusive prefix over the PA_BLOCKS counts (in place),
// row total out. Grid = nbk blocks.
__global__ __launch_bounds__(512)
void row_scan_kernel(int* __restrict__ hist_d, int* __restrict__ Td, int nbk) {
    __shared__ int tmp[512];
    int* row = hist_d + (size_t)blockIdx.x * PA_BLOCKS;
    const int t = threadIdx.x;
    int v = (t < PA_BLOCKS) ? row[t] : 0;
    tmp[t] = v;
    __syncthreads();
    for (int off = 1; off < 512; off <<= 1) {
        int u = (t >= off) ? tmp[t - off] : 0;
        __syncthreads();
        tmp[t] += u;
        __syncthreads();
    }
    if (t < PA_BLOCKS) row[t] = tmp[t] - v;      // exclusive within row
    if (t == 511) Td[blockIdx.x] = tmp[511];     // row total
}

// A3: exclusive scan of the bucket totals, in place (nbk <= 1024).
__global__ __launch_bounds__(1024)
void tot_scan_kernel(int* __restrict__ Td, int nbk) {
    __shared__ int tmp[1024];
    const int t = threadIdx.x;
    int v = (t < nbk) ? Td[t] : 0;
    tmp[t] = v;
    __syncthreads();
    for (int off = 1; off < 1024; off <<= 1) {
        int u = (t >= off) ? tmp[t - off] : 0;
        __syncthreads();
        tmp[t] += u;
        __syncthreads();
    }
    if (t < nbk) Td[t] = tmp[t] - v;
}

// A4: partition scatter. ebuf gets (dst&127)<<17 | src, bucketed by dst>>7.
__global__ __launch_bounds__(256)
void part_scatter_kernel(const int* __restrict__ src, const int* __restrict__ dst,
                         const int* __restrict__ hist_d, const int* __restrict__ Td,
                         int* __restrict__ ebuf, int nbk, int E, int slice_len) {
    __shared__ int cur_d[MAX_NBK];
    const int b = blockIdx.x;
    for (int i = threadIdx.x; i < nbk; i += 256)
        cur_d[i] = Td[i] + hist_d[(size_t)i * PA_BLOCKS + b];
    __syncthreads();
    const int beg = b * slice_len;
    const int end = min(beg + slice_len, E);
    for (int i = beg + threadIdx.x; i < end; i += 256) {
        int d = dst[i], s = src[i];
        int pd = atomicAdd(&cur_d[d >> BKT_SHIFT], 1);   // LDS atomic
        ebuf[pd] = ((d & (BKT_W - 1)) << 17) | s;
    }
}

// B: per-bucket finalize. Emits cnt_in, row_ptr, csr_src (all writes stay
// inside this bucket's ~8KB window -> L2-local).
__global__ __launch_bounds__(256)
void bucket_csr_kernel(const int* __restrict__ ebuf,
                       const int* __restrict__ Td,
                       int* __restrict__ csr_src,
                       int* __restrict__ cnt_in,
                       int* __restrict__ row_ptr,
                       int nbk, int N, int E) {
    __shared__ int cnt[BKT_W];
    __shared__ int rp[BKT_W];
    __shared__ int cur[BKT_W];
    const int k = blockIdx.x;
    const int lo = k << BKT_SHIFT;
    const int span = min(BKT_W, N - lo);
    const int db = Td[k], de = (k + 1 < nbk) ? Td[k + 1] : E;
    const int t = threadIdx.x;

    if (t < BKT_W) cnt[t] = 0;
    __syncthreads();
    for (int i = db + t; i < de; i += 256) atomicAdd(&cnt[ebuf[i] >> 17], 1);
    __syncthreads();
    if (t < BKT_W) rp[t] = cnt[t];
    __syncthreads();
    for (int off = 1; off < BKT_W; off <<= 1) {
        int v = (t < BKT_W && t >= off) ? rp[t - off] : 0;
        __syncthreads();
        if (t < BKT_W) rp[t] += v;
        __syncthreads();
    }
    if (t < span) {
        row_ptr[lo + t] = db + rp[t] - cnt[t];
        cnt_in[lo + t]  = cnt[t];
    }
    __syncthreads();
    if (t < BKT_W) cur[t] = db + rp[t] - cnt[t];
    __syncthreads();
    for (int i = db + t; i < de; i += 256) {
        int p = ebuf[i];
        int pos = atomicAdd(&cur[p >> 17], 1);           // LDS atomic
        csr_src[pos] = p & 0x1FFFF;
    }
    if (k == 0 && t == 0) row_ptr[N] = E;
}

// MFMA GEMM: Y[n][j] = (sum_k X[n][k] * W[k][j]) * rsqrt(max(cnt_out[n],1)),
// stored fp16. hi/lo fp16 split: X=Xh+Xl, W=Wh+Wl (each to 2^-22 rel);
// D = Xh*Wh + Xh*Wl + Xl*Wh via mfma_f32_16x16x32_f16, fp32 accumulate.
// Block = 64 rows x 64 cols, 4 waves (wave = 16-row band, 4 col-tiles).
// W staged transposed in LDS, +8-half row pad (bank stride 4 -> 2-way, free).
// A-frags: lane reads 8 consecutive fp32 of its row (2x dwordx4), cvt in-reg.
template <int K>
__global__ __launch_bounds__(256)
void gemm_scale_kernel(const float* __restrict__ X, const float* __restrict__ W,
                       const int* __restrict__ cnt_out,
                       __half* __restrict__ Y, int N) {
    __shared__ _Float16 Wt[2][64][K + 8];   // [hi/lo][col][k]
    const int t = threadIdx.x;
    for (int i = t; i < K * 64; i += 256) {
        const int k = i >> 6, j = i & 63;
        const float w = W[i];
        const _Float16 hi = (_Float16)w;
        Wt[0][j][k] = hi;
        Wt[1][j][k] = (_Float16)(w - (float)hi);
    }
    __syncthreads();

    const int wid  = t >> 6;
    const int lane = t & 63;
    const int col  = lane & 15;
    const int kg   = (lane >> 4) * 8;        // lane's k-offset within a 32-chunk

    const int rowA = blockIdx.x * 64 + wid * 16 + col;   // A-frag row
    const size_t xbase = (size_t)min(rowA, N - 1) * K;

    f32x4 acc0 = {}, acc1 = {}, acc2 = {}, acc3 = {};

#pragma unroll
    for (int ks = 0; ks < K; ks += 32) {
        float4 xa = *(const float4*)&X[xbase + ks + kg];
        float4 xb = *(const float4*)&X[xbase + ks + kg + 4];
        const float xs[8] = {xa.x, xa.y, xa.z, xa.w, xb.x, xb.y, xb.z, xb.w};
        f16x8 ahi, alo;
#pragma unroll
        for (int j = 0; j < 8; ++j) {
            const _Float16 h = (_Float16)xs[j];
            ahi[j] = h;
            alo[j] = (_Float16)(xs[j] - (float)h);
        }
#pragma unroll
        for (int tile = 0; tile < 4; ++tile) {
            const f16x8 bhi = *(const f16x8*)&Wt[0][col + 16 * tile][ks + kg];
            const f16x8 blo = *(const f16x8*)&Wt[1][col + 16 * tile][ks + kg];
            f32x4* acc = (tile == 0) ? &acc0 : (tile == 1) ? &acc1
                       : (tile == 2) ? &acc2 : &acc3;
            *acc = __builtin_amdgcn_mfma_f32_16x16x32_f16(ahi, bhi, *acc, 0, 0, 0);
            *acc = __builtin_amdgcn_mfma_f32_16x16x32_f16(alo, bhi, *acc, 0, 0, 0);
            *acc = __builtin_amdgcn_mfma_f32_16x16x32_f16(ahi, blo, *acc, 0, 0, 0);
        }
    }

    // D layout: col = lane&15, row = (lane>>4)*4 + reg   [m89-verified]
    const int rbase = blockIdx.x * 64 + wid * 16 + (lane >> 4) * 4;
#pragma unroll
    for (int r = 0; r < 4; ++r) {
        const int rr = rbase + r;
        if (rr < N) {
            const float sc = rsqrtf((float)max(cnt_out[rr], 1));
            __half* yp = &Y[(size_t)rr * 64 + col];
            yp[0]  = __float2half_rn(acc0[r] * sc);
            yp[16] = __float2half_rn(acc1[r] * sc);
            yp[32] = __float2half_rn(acc2[r] * sc);
            yp[48] = __float2half_rn(acc3[r] * sc);
        }
    }
}

// out[n][f] = (sum_{in-edges} Y[src][f]) * rsqrt(max(cnt_in[n],1)) + bias[f]
// Half-wave (32 lanes) per node; lane = one half2 feature pair.
// Clamped unroll-8 edge loop: EVERY row runs with 8 gathers in flight.
template <bool RELU>
__global__ __launch_bounds__(256)
void aggregate_kernel(const __half* __restrict__ Y,
                      const int* __restrict__ row_ptr,
                      const int* __restrict__ csr_src,
                      const int* __restrict__ cnt_in,
                      const float* __restrict__ bias,
                      float* __restrict__ out, int N) {
    const int n = blockIdx.x * 8 + (threadIdx.x >> 5);
    if (n >= N) return;
    const int fp = threadIdx.x & 31;          // features 2*fp, 2*fp+1

    const int start = row_ptr[n];
    const int end   = row_ptr[n + 1];
    const int last  = end - 1;

    float2 acc = {0.f, 0.f};
    for (int e = start; e < end; e += 8) {
        int idx[8];
#pragma unroll
        for (int j = 0; j < 8; ++j) idx[j] = csr_src[min(e + j, last)];
        float2 v[8];
#pragma unroll
        for (int j = 0; j < 8; ++j)
            v[j] = __half22float2(*((const __half2*)(Y + ((size_t)idx[j] << 6)) + fp));
#pragma unroll
        for (int j = 0; j < 8; ++j)
            if (e + j < end) { acc.x += v[j].x; acc.y += v[j].y; }
    }

    const float sc = rsqrtf((float)max(cnt_in[n], 1));
    float2 o;
    o.x = acc.x * sc + bias[2 * fp];
    o.y = acc.y * sc + bias[2 * fp + 1];
    if (RELU) { o.x = fmaxf(o.x, 0.f); o.y = fmaxf(o.y, 0.f); }
    *(float2*)&out[((size_t)n << 6) + 2 * fp] = o;
}

extern "C" void kernel_launch(void* const* d_in, const int* in_sizes, int n_in,
                              void* d_out, int out_size, void* d_ws, size_t ws_size,
                              hipStream_t stream) {
    const float* x   = (const float*)d_in[0];
    const int*   src = (const int*)d_in[1];
    const int*   dst = (const int*)d_in[2];
    const float* W1  = (const float*)d_in[3];
    const float* b1  = (const float*)d_in[4];
    const float* W2  = (const float*)d_in[5];
    const float* b2  = (const float*)d_in[6];
    float* out = (float*)d_out;

    const int N = in_sizes[0] / 128;   // 100000
    const int E = in_sizes[1];         // 1600000

    const int nbk = (N + BKT_W - 1) >> BKT_SHIFT;          // 782 buckets
    const int M = nbk * PA_BLOCKS;

    // Workspace (~24 MB). d_out doubles as the hidden-layer buffer.
    char* ws = (char*)d_ws;
    size_t off = 0;
    __half* Y       = (__half*)(ws + off); off = align256(off + (size_t)N * 64 * sizeof(__half));
    int* csr_src    = (int*)(ws + off);    off = align256(off + (size_t)E * sizeof(int));
    int* ebuf       = (int*)(ws + off);    off = align256(off + (size_t)E * sizeof(int));
    int* hist_d     = (int*)(ws + off);    off = align256(off + (size_t)M * sizeof(int));
    int* Td         = (int*)(ws + off);    off = align256(off + (size_t)nbk * sizeof(int));
    int* cnt_out    = (int*)(ws + off);    off = align256(off + (size_t)N * sizeof(int));
    int* cnt_in     = (int*)(ws + off);    off = align256(off + (size_t)N * sizeof(int));
    int* row_ptr    = (int*)(ws + off);    off = align256(off + (size_t)(N + 1) * sizeof(int));

    const int pslice = (E + PA_BLOCKS - 1) / PA_BLOCKS;

    // Radix-partition CSR build + degree counts
    hipMemsetAsync(cnt_out, 0, (size_t)N * sizeof(int), stream);
    part_hist_kernel<<<PA_BLOCKS, 256, 0, stream>>>(src, dst, hist_d, cnt_out, nbk, E, pslice);
    row_scan_kernel<<<nbk, 512, 0, stream>>>(hist_d, Td, nbk);
    tot_scan_kernel<<<1, 1024, 0, stream>>>(Td, nbk);
    part_scatter_kernel<<<PA_BLOCKS, 256, 0, stream>>>(src, dst, hist_d, Td, ebuf, nbk, E, pslice);
    bucket_csr_kernel<<<nbk, 256, 0, stream>>>(ebuf, Td, csr_src, cnt_in, row_ptr, nbk, N, E);

    const int gemm_blocks = (N + 63) / 64;
    const int agg_blocks  = (N + 7) / 8;

    // Layer 1: Y = fp16[(X @ W1) * rs_out] ; agg -> d_out (hidden, relu)
    gemm_scale_kernel<128><<<gemm_blocks, 256, 0, stream>>>(x, W1, cnt_out, Y, N);
    aggregate_kernel<true><<<agg_blocks, 256, 0, stream>>>(Y, row_ptr, csr_src, cnt_in, b1, out, N);

    // Layer 2: Y = fp16[(H @ W2) * rs_out] ; agg -> d_out (final)
    gemm_scale_kernel<64><<<gemm_blocks, 256, 0, stream>>>(out, W2, cnt_out, Y, N);
    aggregate_kernel<false><<<agg_blocks, 256, 0, stream>>>(Y, row_ptr, csr_src, cnt_in, b2, out, N);
}

// Round 4
// 284.174 us; speedup vs baseline: 1.0673x; 1.0673x over previous
//
#include <hip/hip_runtime.h>
#include <hip/hip_fp16.h>

// GCN 2-layer: out = D_in^-1/2 A D_out^-1/2 (relu(D_in^-1/2 A D_out^-1/2 X W1 + b1)) W2 + b2
// Strategy: project-then-aggregate; CSR-by-dst via DUAL radix partition,
// zero device-scope atomics anywhere.
// R7: radix CSR 368us. R8: dual partition 354us.
// R9 FAILED (1604us): LDS fp32 atomicAdd aggregate -> CAS serialization.
// R10: half-wave/node aggregate, clamped unroll-8: 302us.
// R11 NEUTRAL (303us): MFMA GEMM saved ~40us but cnt_out via global atomics
//      cost exactly that (part_hist 71us, WRITE_SIZE 60MB — every device
//      atomic is a fabric transaction on multi-XCD). Lesson: no global
//      atomics >1M ops, fire-and-forget included.
// R12: dual-partition chain (R10) + MFMA GEMM (R11) + aggregate batch 8->16
//      gathers in flight per lane.

static inline size_t align256(size_t x) { return (x + 255) & ~(size_t)255; }

#define BKT_SHIFT 7
#define BKT_W 128              // nodes per bucket window
#define MAX_NBK 800            // LDS sizing guard (N <= 102400)
#define PA_BLOCKS 416          // partition pass blocks

typedef _Float16 f16x8 __attribute__((ext_vector_type(8)));
typedef float f32x4 __attribute__((ext_vector_type(4)));

// A1: per-block bucket histograms of BOTH dst>>7 and src>>7.
__global__ __launch_bounds__(256)
void part_hist_kernel(const int* __restrict__ src, const int* __restrict__ dst,
                      int* __restrict__ hist_d, int* __restrict__ hist_s,
                      int nbk, int E, int slice_len) {
    __shared__ int hd[MAX_NBK];
    __shared__ int hs[MAX_NBK];
    const int b = blockIdx.x;
    for (int i = threadIdx.x; i < nbk; i += 256) { hd[i] = 0; hs[i] = 0; }
    __syncthreads();
    const int beg = b * slice_len;
    const int end = min(beg + slice_len, E);
    for (int i = beg + threadIdx.x; i < end; i += 256) {
        atomicAdd(&hd[dst[i] >> BKT_SHIFT], 1);   // LDS atomics (int: native)
        atomicAdd(&hs[src[i] >> BKT_SHIFT], 1);
    }
    __syncthreads();
    for (int i = threadIdx.x; i < nbk; i += 256) {
        hist_d[(size_t)i * PA_BLOCKS + b] = hd[i];
        hist_s[(size_t)i * PA_BLOCKS + b] = hs[i];
    }
}

// A2: per-bucket-row exclusive prefix over the PA_BLOCKS counts (in place),
// row total out. Grid = 2*nbk blocks (dst rows then src rows).
__global__ __launch_bounds__(512)
void row_scan_kernel(int* __restrict__ hist_d, int* __restrict__ hist_s,
                     int* __restrict__ Td, int* __restrict__ Ts, int nbk) {
    __shared__ int tmp[512];
    int j = blockIdx.x;
    int* row;
    int* T;
    if (j < nbk) { row = hist_d + (size_t)j * PA_BLOCKS; T = Td; }
    else         { j -= nbk; row = hist_s + (size_t)j * PA_BLOCKS; T = Ts; }
    const int t = threadIdx.x;
    int v = (t < PA_BLOCKS) ? row[t] : 0;
    tmp[t] = v;
    __syncthreads();
    for (int off = 1; off < 512; off <<= 1) {
        int u = (t >= off) ? tmp[t - off] : 0;
        __syncthreads();
        tmp[t] += u;
        __syncthreads();
    }
    if (t < PA_BLOCKS) row[t] = tmp[t] - v;      // exclusive within row
    if (t == 511) T[j] = tmp[511];               // row total
}

// A3: exclusive scan of the bucket totals (both tables), in place.
__global__ __launch_bounds__(1024)
void tot_scan_kernel(int* __restrict__ Td, int* __restrict__ Ts, int nbk) {
    __shared__ int tmp[1024];
    const int t = threadIdx.x;
    int v = (t < nbk) ? Td[t] : 0;
    tmp[t] = v;
    __syncthreads();
    for (int off = 1; off < 1024; off <<= 1) {
        int u = (t >= off) ? tmp[t - off] : 0;
        __syncthreads();
        tmp[t] += u;
        __syncthreads();
    }
    if (t < nbk) Td[t] = tmp[t] - v;
    __syncthreads();
    int v2 = (t < nbk) ? Ts[t] : 0;
    tmp[t] = v2;
    __syncthreads();
    for (int off = 1; off < 1024; off <<= 1) {
        int u = (t >= off) ? tmp[t - off] : 0;
        __syncthreads();
        tmp[t] += u;
        __syncthreads();
    }
    if (t < nbk) Ts[t] = tmp[t] - v2;
}

// A4: partition scatter. ebuf gets (dst&127)<<17 | src (dst-bucketed);
// sbuf gets 1-byte src&127 (src-bucketed) for the cnt_out count.
__global__ __launch_bounds__(256)
void part_scatter_kernel(const int* __restrict__ src, const int* __restrict__ dst,
                         const int* __restrict__ hist_d, const int* __restrict__ hist_s,
                         const int* __restrict__ Td, const int* __restrict__ Ts,
                         int* __restrict__ ebuf, unsigned char* __restrict__ sbuf,
                         int nbk, int E, int slice_len) {
    __shared__ int cur_d[MAX_NBK];
    __shared__ int cur_s[MAX_NBK];
    const int b = blockIdx.x;
    for (int i = threadIdx.x; i < nbk; i += 256) {
        cur_d[i] = Td[i] + hist_d[(size_t)i * PA_BLOCKS + b];
        cur_s[i] = Ts[i] + hist_s[(size_t)i * PA_BLOCKS + b];
    }
    __syncthreads();
    const int beg = b * slice_len;
    const int end = min(beg + slice_len, E);
    for (int i = beg + threadIdx.x; i < end; i += 256) {
        int d = dst[i], s = src[i];
        int pd = atomicAdd(&cur_d[d >> BKT_SHIFT], 1);   // LDS atomic
        ebuf[pd] = ((d & (BKT_W - 1)) << 17) | s;
        int ps = atomicAdd(&cur_s[s >> BKT_SHIFT], 1);   // LDS atomic
        sbuf[ps] = (unsigned char)(s & (BKT_W - 1));
    }
}

// B: per-bucket finalize. Emits cnt_in, cnt_out, row_ptr, csr_src.
__global__ __launch_bounds__(256)
void bucket_csr_kernel(const int* __restrict__ ebuf,
                       const unsigned char* __restrict__ sbuf,
                       const int* __restrict__ Td, const int* __restrict__ Ts,
                       int* __restrict__ csr_src,
                       int* __restrict__ cnt_in, int* __restrict__ cnt_out,
                       int* __restrict__ row_ptr,
                       int nbk, int N, int E) {
    __shared__ int cnt[BKT_W];
    __shared__ int rp[BKT_W];
    __shared__ int cur[BKT_W];
    __shared__ int cnts[BKT_W];
    const int k = blockIdx.x;
    const int lo = k << BKT_SHIFT;
    const int span = min(BKT_W, N - lo);
    const int db = Td[k], de = (k + 1 < nbk) ? Td[k + 1] : E;
    const int sb = Ts[k], se = (k + 1 < nbk) ? Ts[k + 1] : E;
    const int t = threadIdx.x;

    if (t < BKT_W) { cnt[t] = 0; cnts[t] = 0; }
    __syncthreads();
    for (int i = db + t; i < de; i += 256) atomicAdd(&cnt[ebuf[i] >> 17], 1);
    for (int i = sb + t; i < se; i += 256) atomicAdd(&cnts[sbuf[i]], 1);
    __syncthreads();
    if (t < BKT_W) rp[t] = cnt[t];
    __syncthreads();
    for (int off = 1; off < BKT_W; off <<= 1) {
        int v = (t < BKT_W && t >= off) ? rp[t - off] : 0;
        __syncthreads();
        if (t < BKT_W) rp[t] += v;
        __syncthreads();
    }
    if (t < span) {
        row_ptr[lo + t] = db + rp[t] - cnt[t];
        cnt_in[lo + t]  = cnt[t];
        cnt_out[lo + t] = cnts[t];
    }
    __syncthreads();
    if (t < BKT_W) cur[t] = db + rp[t] - cnt[t];
    __syncthreads();
    for (int i = db + t; i < de; i += 256) {
        int p = ebuf[i];
        int pos = atomicAdd(&cur[p >> 17], 1);           // LDS atomic
        csr_src[pos] = p & 0x1FFFF;
    }
    if (k == 0 && t == 0) row_ptr[N] = E;
}

// MFMA GEMM: Y[n][j] = (sum_k X[n][k] * W[k][j]) * rsqrt(max(cnt_out[n],1)),
// stored fp16. hi/lo fp16 split: X=Xh+Xl, W=Wh+Wl (each to 2^-22 rel);
// D = Xh*Wh + Xh*Wl + Xl*Wh via mfma_f32_16x16x32_f16, fp32 accumulate.
// Block = 64 rows x 64 cols, 4 waves (wave = 16-row band, 4 col-tiles).
// W staged transposed in LDS, +8-half row pad (bank stride 4 -> 2-way, free).
template <int K>
__global__ __launch_bounds__(256)
void gemm_scale_kernel(const float* __restrict__ X, const float* __restrict__ W,
                       const int* __restrict__ cnt_out,
                       __half* __restrict__ Y, int N) {
    __shared__ _Float16 Wt[2][64][K + 8];   // [hi/lo][col][k]
    const int t = threadIdx.x;
    for (int i = t; i < K * 64; i += 256) {
        const int k = i >> 6, j = i & 63;
        const float w = W[i];
        const _Float16 hi = (_Float16)w;
        Wt[0][j][k] = hi;
        Wt[1][j][k] = (_Float16)(w - (float)hi);
    }
    __syncthreads();

    const int wid  = t >> 6;
    const int lane = t & 63;
    const int col  = lane & 15;
    const int kg   = (lane >> 4) * 8;        // lane's k-offset within a 32-chunk

    const int rowA = blockIdx.x * 64 + wid * 16 + col;   // A-frag row
    const size_t xbase = (size_t)min(rowA, N - 1) * K;

    f32x4 acc0 = {}, acc1 = {}, acc2 = {}, acc3 = {};

#pragma unroll
    for (int ks = 0; ks < K; ks += 32) {
        float4 xa = *(const float4*)&X[xbase + ks + kg];
        float4 xb = *(const float4*)&X[xbase + ks + kg + 4];
        const float xs[8] = {xa.x, xa.y, xa.z, xa.w, xb.x, xb.y, xb.z, xb.w};
        f16x8 ahi, alo;
#pragma unroll
        for (int j = 0; j < 8; ++j) {
            const _Float16 h = (_Float16)xs[j];
            ahi[j] = h;
            alo[j] = (_Float16)(xs[j] - (float)h);
        }
#pragma unroll
        for (int tile = 0; tile < 4; ++tile) {
            const f16x8 bhi = *(const f16x8*)&Wt[0][col + 16 * tile][ks + kg];
            const f16x8 blo = *(const f16x8*)&Wt[1][col + 16 * tile][ks + kg];
            f32x4* acc = (tile == 0) ? &acc0 : (tile == 1) ? &acc1
                       : (tile == 2) ? &acc2 : &acc3;
            *acc = __builtin_amdgcn_mfma_f32_16x16x32_f16(ahi, bhi, *acc, 0, 0, 0);
            *acc = __builtin_amdgcn_mfma_f32_16x16x32_f16(alo, bhi, *acc, 0, 0, 0);
            *acc = __builtin_amdgcn_mfma_f32_16x16x32_f16(ahi, blo, *acc, 0, 0, 0);
        }
    }

    // D layout: col = lane&15, row = (lane>>4)*4 + reg   [m89-verified]
    const int rbase = blockIdx.x * 64 + wid * 16 + (lane >> 4) * 4;
#pragma unroll
    for (int r = 0; r < 4; ++r) {
        const int rr = rbase + r;
        if (rr < N) {
            const float sc = rsqrtf((float)max(cnt_out[rr], 1));
            __half* yp = &Y[(size_t)rr * 64 + col];
            yp[0]  = __float2half_rn(acc0[r] * sc);
            yp[16] = __float2half_rn(acc1[r] * sc);
            yp[32] = __float2half_rn(acc2[r] * sc);
            yp[48] = __float2half_rn(acc3[r] * sc);
        }
    }
}

// out[n][f] = (sum_{in-edges} Y[src][f]) * rsqrt(max(cnt_in[n],1)) + bias[f]
// Half-wave (32 lanes) per node; lane = one half2 feature pair.
// Clamped batch-16 edge loop: EVERY row runs with 16 gathers in flight
// (clamp-duplicates hit the same cacheline ~ free). No atomics, no shuffles.
template <bool RELU>
__global__ __launch_bounds__(256)
void aggregate_kernel(const __half* __restrict__ Y,
                      const int* __restrict__ row_ptr,
                      const int* __restrict__ csr_src,
                      const int* __restrict__ cnt_in,
                      const float* __restrict__ bias,
                      float* __restrict__ out, int N) {
    const int n = blockIdx.x * 8 + (threadIdx.x >> 5);
    if (n >= N) return;
    const int fp = threadIdx.x & 31;          // features 2*fp, 2*fp+1

    const int start = row_ptr[n];
    const int end   = row_ptr[n + 1];
    const int last  = end - 1;

    float2 acc = {0.f, 0.f};
    for (int e = start; e < end; e += 16) {
        int idx[16];
#pragma unroll
        for (int j = 0; j < 16; ++j) idx[j] = csr_src[min(e + j, last)];
        float2 v[16];
#pragma unroll
        for (int j = 0; j < 16; ++j)
            v[j] = __half22float2(*((const __half2*)(Y + ((size_t)idx[j] << 6)) + fp));
#pragma unroll
        for (int j = 0; j < 16; ++j)
            if (e + j < end) { acc.x += v[j].x; acc.y += v[j].y; }
    }

    const float sc = rsqrtf((float)max(cnt_in[n], 1));
    float2 o;
    o.x = acc.x * sc + bias[2 * fp];
    o.y = acc.y * sc + bias[2 * fp + 1];
    if (RELU) { o.x = fmaxf(o.x, 0.f); o.y = fmaxf(o.y, 0.f); }
    *(float2*)&out[((size_t)n << 6) + 2 * fp] = o;
}

extern "C" void kernel_launch(void* const* d_in, const int* in_sizes, int n_in,
                              void* d_out, int out_size, void* d_ws, size_t ws_size,
                              hipStream_t stream) {
    const float* x   = (const float*)d_in[0];
    const int*   src = (const int*)d_in[1];
    const int*   dst = (const int*)d_in[2];
    const float* W1  = (const float*)d_in[3];
    const float* b1  = (const float*)d_in[4];
    const float* W2  = (const float*)d_in[5];
    const float* b2  = (const float*)d_in[6];
    float* out = (float*)d_out;

    const int N = in_sizes[0] / 128;   // 100000
    const int E = in_sizes[1];         // 1600000

    const int nbk = (N + BKT_W - 1) >> BKT_SHIFT;          // 782 buckets
    const int M = nbk * PA_BLOCKS;

    // Workspace (~30 MB). d_out doubles as the hidden-layer buffer.
    char* ws = (char*)d_ws;
    size_t off = 0;
    __half* Y       = (__half*)(ws + off); off = align256(off + (size_t)N * 64 * sizeof(__half));
    int* csr_src    = (int*)(ws + off);    off = align256(off + (size_t)E * sizeof(int));
    int* ebuf       = (int*)(ws + off);    off = align256(off + (size_t)E * sizeof(int));
    unsigned char* sbuf = (unsigned char*)(ws + off); off = align256(off + (size_t)E);
    int* hist_d     = (int*)(ws + off);    off = align256(off + (size_t)M * sizeof(int));
    int* hist_s     = (int*)(ws + off);    off = align256(off + (size_t)M * sizeof(int));
    int* Td         = (int*)(ws + off);    off = align256(off + (size_t)nbk * sizeof(int));
    int* Ts         = (int*)(ws + off);    off = align256(off + (size_t)nbk * sizeof(int));
    int* cnt_out    = (int*)(ws + off);    off = align256(off + (size_t)N * sizeof(int));
    int* cnt_in     = (int*)(ws + off);    off = align256(off + (size_t)N * sizeof(int));
    int* row_ptr    = (int*)(ws + off);    off = align256(off + (size_t)(N + 1) * sizeof(int));

    const int pslice = (E + PA_BLOCKS - 1) / PA_BLOCKS;

    // Dual radix-partition CSR build + degree counts (zero device atomics)
    part_hist_kernel<<<PA_BLOCKS, 256, 0, stream>>>(src, dst, hist_d, hist_s, nbk, E, pslice);
    row_scan_kernel<<<2 * nbk, 512, 0, stream>>>(hist_d, hist_s, Td, Ts, nbk);
    tot_scan_kernel<<<1, 1024, 0, stream>>>(Td, Ts, nbk);
    part_scatter_kernel<<<PA_BLOCKS, 256, 0, stream>>>(src, dst, hist_d, hist_s, Td, Ts,
                                                       ebuf, sbuf, nbk, E, pslice);
    bucket_csr_kernel<<<nbk, 256, 0, stream>>>(ebuf, sbuf, Td, Ts, csr_src,
                                               cnt_in, cnt_out, row_ptr, nbk, N, E);

    const int gemm_blocks = (N + 63) / 64;
    const int agg_blocks  = (N + 7) / 8;

    // Layer 1: Y = fp16[(X @ W1) * rs_out] ; agg -> d_out (hidden, relu)
    gemm_scale_kernel<128><<<gemm_blocks, 256, 0, stream>>>(x, W1, cnt_out, Y, N);
    aggregate_kernel<true><<<agg_blocks, 256, 0, stream>>>(Y, row_ptr, csr_src, cnt_in, b1, out, N);

    // Layer 2: Y = fp16[(H @ W2) * rs_out] ; agg -> d_out (final)
    gemm_scale_kernel<64><<<gemm_blocks, 256, 0, stream>>>(out, W2, cnt_out, Y, N);
    aggregate_kernel<false><<<agg_blocks, 256, 0, stream>>>(Y, row_ptr, csr_src, cnt_in, b2, out, N);
}

// Round 5
// 267.381 us; speedup vs baseline: 1.1343x; 1.0628x over previous
//
#include <hip/hip_runtime.h>
#include <hip/hip_fp16.h>

// GCN 2-layer: out = D_in^-1/2 A D_out^-1/2 (relu(D_in^-1/2 A D_out^-1/2 X W1 + b1)) W2 + b2
// Strategy: project-then-aggregate; CSR-by-dst via DUAL radix partition,
// zero device-scope atomics anywhere.
// R7: radix CSR 368us. R8: dual partition 354us.
// R9 FAILED (1604us): LDS fp32 atomicAdd aggregate -> CAS serialization.
// R10: half-wave/node aggregate, clamped unroll-8: 302us.
// R11 NEUTRAL (303us): MFMA GEMM saved ~40us but global-atomic cnt_out cost
//      the same (fabric transaction per atomic on multi-XCD).
// R12: dual partition + MFMA GEMM + batch-16: 284us. Aggregate top (47us,
//      VALUBusy 62% -> VALU-issue-bound on 32-lane/4B-gather addressing).
// R13: (a) aggregate 16 lanes/node x 8B gathers (4 nodes/wave, batch 12):
//      halves per-edge address VALU + VMEM instrs, 2x edges in flight.
//      (b) delete tot_scan dispatch: part_scatter scans bucket totals in
//      LDS per block; bucket_csr computes its prefix by reduction.

static inline size_t align256(size_t x) { return (x + 255) & ~(size_t)255; }

#define BKT_SHIFT 7
#define BKT_W 128              // nodes per bucket window
#define MAX_NBK 800            // LDS sizing guard (N <= 102400)
#define PA_BLOCKS 416          // partition pass blocks

typedef _Float16 f16x8 __attribute__((ext_vector_type(8)));
typedef float f32x4 __attribute__((ext_vector_type(4)));

// A1: per-block bucket histograms of BOTH dst>>7 and src>>7.
__global__ __launch_bounds__(256)
void part_hist_kernel(const int* __restrict__ src, const int* __restrict__ dst,
                      int* __restrict__ hist_d, int* __restrict__ hist_s,
                      int nbk, int E, int slice_len) {
    __shared__ int hd[MAX_NBK];
    __shared__ int hs[MAX_NBK];
    const int b = blockIdx.x;
    for (int i = threadIdx.x; i < nbk; i += 256) { hd[i] = 0; hs[i] = 0; }
    __syncthreads();
    const int beg = b * slice_len;
    const int end = min(beg + slice_len, E);
    for (int i = beg + threadIdx.x; i < end; i += 256) {
        atomicAdd(&hd[dst[i] >> BKT_SHIFT], 1);   // LDS atomics (int: native)
        atomicAdd(&hs[src[i] >> BKT_SHIFT], 1);
    }
    __syncthreads();
    for (int i = threadIdx.x; i < nbk; i += 256) {
        hist_d[(size_t)i * PA_BLOCKS + b] = hd[i];
        hist_s[(size_t)i * PA_BLOCKS + b] = hs[i];
    }
}

// A2: per-bucket-row exclusive prefix over the PA_BLOCKS counts (in place),
// row total out (totals stay UN-scanned; consumers scan locally).
// Grid = 2*nbk blocks (dst rows then src rows).
__global__ __launch_bounds__(512)
void row_scan_kernel(int* __restrict__ hist_d, int* __restrict__ hist_s,
                     int* __restrict__ Td, int* __restrict__ Ts, int nbk) {
    __shared__ int tmp[512];
    int j = blockIdx.x;
    int* row;
    int* T;
    if (j < nbk) { row = hist_d + (size_t)j * PA_BLOCKS; T = Td; }
    else         { j -= nbk; row = hist_s + (size_t)j * PA_BLOCKS; T = Ts; }
    const int t = threadIdx.x;
    int v = (t < PA_BLOCKS) ? row[t] : 0;
    tmp[t] = v;
    __syncthreads();
    for (int off = 1; off < 512; off <<= 1) {
        int u = (t >= off) ? tmp[t - off] : 0;
        __syncthreads();
        tmp[t] += u;
        __syncthreads();
    }
    if (t < PA_BLOCKS) row[t] = tmp[t] - v;      // exclusive within row
    if (t == 511) T[j] = tmp[511];               // row total
}

// A4: partition scatter. Computes the exclusive scan of the bucket totals
// in LDS (replaces the old tot_scan kernel), then scatters.
// ebuf gets (dst&127)<<17 | src (dst-bucketed); sbuf gets 1-byte src&127.
__global__ __launch_bounds__(256)
void part_scatter_kernel(const int* __restrict__ src, const int* __restrict__ dst,
                         const int* __restrict__ hist_d, const int* __restrict__ hist_s,
                         const int* __restrict__ Td, const int* __restrict__ Ts,
                         int* __restrict__ ebuf, unsigned char* __restrict__ sbuf,
                         int nbk, int E, int slice_len) {
    __shared__ int cur_d[MAX_NBK];
    __shared__ int cur_s[MAX_NBK];
    __shared__ int csum[256];
    const int b = blockIdx.x;
    const int t = threadIdx.x;

    // exclusive scan of totals: Td -> cur_d, Ts -> cur_s
#pragma unroll
    for (int p = 0; p < 2; ++p) {
        const int* T = p ? Ts : Td;
        int* curx = p ? cur_s : cur_d;
        const int base = 4 * t;
        int v[4];
        int s = 0;
#pragma unroll
        for (int q = 0; q < 4; ++q) {
            v[q] = (base + q < nbk) ? T[base + q] : 0;
            s += v[q];
        }
        csum[t] = s;
        __syncthreads();
        for (int off = 1; off < 256; off <<= 1) {
            int u = (t >= off) ? csum[t - off] : 0;
            __syncthreads();
            csum[t] += u;
            __syncthreads();
        }
        int run = csum[t] - s;       // exclusive chunk prefix
#pragma unroll
        for (int q = 0; q < 4; ++q) {
            if (base + q < nbk) curx[base + q] = run;
            run += v[q];
        }
        __syncthreads();             // protect csum reuse
    }

    for (int i = t; i < nbk; i += 256) {
        cur_d[i] += hist_d[(size_t)i * PA_BLOCKS + b];
        cur_s[i] += hist_s[(size_t)i * PA_BLOCKS + b];
    }
    __syncthreads();

    const int beg = b * slice_len;
    const int end = min(beg + slice_len, E);
    for (int i = beg + t; i < end; i += 256) {
        int d = dst[i], s = src[i];
        int pd = atomicAdd(&cur_d[d >> BKT_SHIFT], 1);   // LDS atomic
        ebuf[pd] = ((d & (BKT_W - 1)) << 17) | s;
        int ps = atomicAdd(&cur_s[s >> BKT_SHIFT], 1);   // LDS atomic
        sbuf[ps] = (unsigned char)(s & (BKT_W - 1));
    }
}

// B: per-bucket finalize. Computes its bucket base (db/sb) by reducing the
// totals arrays, then emits cnt_in, cnt_out, row_ptr, csr_src.
__global__ __launch_bounds__(256)
void bucket_csr_kernel(const int* __restrict__ ebuf,
                       const unsigned char* __restrict__ sbuf,
                       const int* __restrict__ Td, const int* __restrict__ Ts,
                       int* __restrict__ csr_src,
                       int* __restrict__ cnt_in, int* __restrict__ cnt_out,
                       int* __restrict__ row_ptr,
                       int nbk, int N, int E) {
    __shared__ int cnt[BKT_W];
    __shared__ int rp[BKT_W];
    __shared__ int cur[BKT_W];
    __shared__ int cnts[BKT_W];
    __shared__ int red[256];
    __shared__ int sh_db, sh_sb;
    const int k = blockIdx.x;
    const int lo = k << BKT_SHIFT;
    const int span = min(BKT_W, N - lo);
    const int t = threadIdx.x;

    // db = sum Td[0..k), sb = sum Ts[0..k)
    int s1 = 0, s2 = 0;
    for (int i = t; i < k; i += 256) { s1 += Td[i]; s2 += Ts[i]; }
    red[t] = s1;
    __syncthreads();
    for (int off = 128; off >= 1; off >>= 1) {
        if (t < off) red[t] += red[t + off];
        __syncthreads();
    }
    if (t == 0) sh_db = red[0];
    __syncthreads();
    red[t] = s2;
    __syncthreads();
    for (int off = 128; off >= 1; off >>= 1) {
        if (t < off) red[t] += red[t + off];
        __syncthreads();
    }
    if (t == 0) sh_sb = red[0];
    __syncthreads();
    const int db = sh_db, de = db + Td[k];
    const int sb = sh_sb, se = sb + Ts[k];

    if (t < BKT_W) { cnt[t] = 0; cnts[t] = 0; }
    __syncthreads();
    for (int i = db + t; i < de; i += 256) atomicAdd(&cnt[ebuf[i] >> 17], 1);
    for (int i = sb + t; i < se; i += 256) atomicAdd(&cnts[sbuf[i]], 1);
    __syncthreads();
    if (t < BKT_W) rp[t] = cnt[t];
    __syncthreads();
    for (int off = 1; off < BKT_W; off <<= 1) {
        int v = (t < BKT_W && t >= off) ? rp[t - off] : 0;
        __syncthreads();
        if (t < BKT_W) rp[t] += v;
        __syncthreads();
    }
    if (t < span) {
        row_ptr[lo + t] = db + rp[t] - cnt[t];
        cnt_in[lo + t]  = cnt[t];
        cnt_out[lo + t] = cnts[t];
    }
    __syncthreads();
    if (t < BKT_W) cur[t] = db + rp[t] - cnt[t];
    __syncthreads();
    for (int i = db + t; i < de; i += 256) {
        int p = ebuf[i];
        int pos = atomicAdd(&cur[p >> 17], 1);           // LDS atomic
        csr_src[pos] = p & 0x1FFFF;
    }
    if (k == 0 && t == 0) row_ptr[N] = E;
}

// MFMA GEMM: Y[n][j] = (sum_k X[n][k] * W[k][j]) * rsqrt(max(cnt_out[n],1)),
// stored fp16. hi/lo fp16 split: X=Xh+Xl, W=Wh+Wl (each to 2^-22 rel);
// D = Xh*Wh + Xh*Wl + Xl*Wh via mfma_f32_16x16x32_f16, fp32 accumulate.
template <int K>
__global__ __launch_bounds__(256)
void gemm_scale_kernel(const float* __restrict__ X, const float* __restrict__ W,
                       const int* __restrict__ cnt_out,
                       __half* __restrict__ Y, int N) {
    __shared__ _Float16 Wt[2][64][K + 8];   // [hi/lo][col][k]
    const int t = threadIdx.x;
    for (int i = t; i < K * 64; i += 256) {
        const int k = i >> 6, j = i & 63;
        const float w = W[i];
        const _Float16 hi = (_Float16)w;
        Wt[0][j][k] = hi;
        Wt[1][j][k] = (_Float16)(w - (float)hi);
    }
    __syncthreads();

    const int wid  = t >> 6;
    const int lane = t & 63;
    const int col  = lane & 15;
    const int kg   = (lane >> 4) * 8;        // lane's k-offset within a 32-chunk

    const int rowA = blockIdx.x * 64 + wid * 16 + col;   // A-frag row
    const size_t xbase = (size_t)min(rowA, N - 1) * K;

    f32x4 acc0 = {}, acc1 = {}, acc2 = {}, acc3 = {};

#pragma unroll
    for (int ks = 0; ks < K; ks += 32) {
        float4 xa = *(const float4*)&X[xbase + ks + kg];
        float4 xb = *(const float4*)&X[xbase + ks + kg + 4];
        const float xs[8] = {xa.x, xa.y, xa.z, xa.w, xb.x, xb.y, xb.z, xb.w};
        f16x8 ahi, alo;
#pragma unroll
        for (int j = 0; j < 8; ++j) {
            const _Float16 h = (_Float16)xs[j];
            ahi[j] = h;
            alo[j] = (_Float16)(xs[j] - (float)h);
        }
#pragma unroll
        for (int tile = 0; tile < 4; ++tile) {
            const f16x8 bhi = *(const f16x8*)&Wt[0][col + 16 * tile][ks + kg];
            const f16x8 blo = *(const f16x8*)&Wt[1][col + 16 * tile][ks + kg];
            f32x4* acc = (tile == 0) ? &acc0 : (tile == 1) ? &acc1
                       : (tile == 2) ? &acc2 : &acc3;
            *acc = __builtin_amdgcn_mfma_f32_16x16x32_f16(ahi, bhi, *acc, 0, 0, 0);
            *acc = __builtin_amdgcn_mfma_f32_16x16x32_f16(alo, bhi, *acc, 0, 0, 0);
            *acc = __builtin_amdgcn_mfma_f32_16x16x32_f16(ahi, blo, *acc, 0, 0, 0);
        }
    }

    // D layout: col = lane&15, row = (lane>>4)*4 + reg   [m89-verified]
    const int rbase = blockIdx.x * 64 + wid * 16 + (lane >> 4) * 4;
#pragma unroll
    for (int r = 0; r < 4; ++r) {
        const int rr = rbase + r;
        if (rr < N) {
            const float sc = rsqrtf((float)max(cnt_out[rr], 1));
            __half* yp = &Y[(size_t)rr * 64 + col];
            yp[0]  = __float2half_rn(acc0[r] * sc);
            yp[16] = __float2half_rn(acc1[r] * sc);
            yp[32] = __float2half_rn(acc2[r] * sc);
            yp[48] = __float2half_rn(acc3[r] * sc);
        }
    }
}

// out[n][f] = (sum_{in-edges} Y[src][f]) * rsqrt(max(cnt_in[n],1)) + bias[f]
// 16 lanes per node (4 nodes/wave); lane = 2 half2 feature pairs (8B gather).
// Clamped batch-12 edge loop: EVERY row runs with 12 gathers in flight
// (clamp-duplicates hit the same cacheline ~ free). No atomics, no shuffles.
template <bool RELU>
__global__ __launch_bounds__(256)
void aggregate_kernel(const __half* __restrict__ Y,
                      const int* __restrict__ row_ptr,
                      const int* __restrict__ csr_src,
                      const int* __restrict__ cnt_in,
                      const float* __restrict__ bias,
                      float* __restrict__ out, int N) {
    const int n = blockIdx.x * 16 + (threadIdx.x >> 4);
    if (n >= N) return;
    const int fq = threadIdx.x & 15;          // features 4*fq .. 4*fq+3

    const int start = row_ptr[n];
    const int end   = row_ptr[n + 1];
    const int last  = end - 1;

    float4 acc = {0.f, 0.f, 0.f, 0.f};
    for (int e = start; e < end; e += 12) {
        int idx[12];
#pragma unroll
        for (int j = 0; j < 12; ++j) idx[j] = csr_src[min(e + j, last)];
        uint2 v[12];
#pragma unroll
        for (int j = 0; j < 12; ++j)
            v[j] = *((const uint2*)(Y + ((size_t)idx[j] << 6)) + fq);
#pragma unroll
        for (int j = 0; j < 12; ++j) {
            if (e + j < end) {
                float2 a = __half22float2(*(const __half2*)&v[j].x);
                float2 b = __half22float2(*(const __half2*)&v[j].y);
                acc.x += a.x; acc.y += a.y; acc.z += b.x; acc.w += b.y;
            }
        }
    }

    const float sc = rsqrtf((float)max(cnt_in[n], 1));
    const float4 bb = *(const float4*)&bias[4 * fq];
    float4 o;
    o.x = acc.x * sc + bb.x;
    o.y = acc.y * sc + bb.y;
    o.z = acc.z * sc + bb.z;
    o.w = acc.w * sc + bb.w;
    if (RELU) {
        o.x = fmaxf(o.x, 0.f); o.y = fmaxf(o.y, 0.f);
        o.z = fmaxf(o.z, 0.f); o.w = fmaxf(o.w, 0.f);
    }
    *(float4*)&out[((size_t)n << 6) + 4 * fq] = o;
}

extern "C" void kernel_launch(void* const* d_in, const int* in_sizes, int n_in,
                              void* d_out, int out_size, void* d_ws, size_t ws_size,
                              hipStream_t stream) {
    const float* x   = (const float*)d_in[0];
    const int*   src = (const int*)d_in[1];
    const int*   dst = (const int*)d_in[2];
    const float* W1  = (const float*)d_in[3];
    const float* b1  = (const float*)d_in[4];
    const float* W2  = (const float*)d_in[5];
    const float* b2  = (const float*)d_in[6];
    float* out = (float*)d_out;

    const int N = in_sizes[0] / 128;   // 100000
    const int E = in_sizes[1];         // 1600000

    const int nbk = (N + BKT_W - 1) >> BKT_SHIFT;          // 782 buckets
    const int M = nbk * PA_BLOCKS;

    // Workspace (~30 MB). d_out doubles as the hidden-layer buffer.
    char* ws = (char*)d_ws;
    size_t off = 0;
    __half* Y       = (__half*)(ws + off); off = align256(off + (size_t)N * 64 * sizeof(__half));
    int* csr_src    = (int*)(ws + off);    off = align256(off + (size_t)E * sizeof(int));
    int* ebuf       = (int*)(ws + off);    off = align256(off + (size_t)E * sizeof(int));
    unsigned char* sbuf = (unsigned char*)(ws + off); off = align256(off + (size_t)E);
    int* hist_d     = (int*)(ws + off);    off = align256(off + (size_t)M * sizeof(int));
    int* hist_s     = (int*)(ws + off);    off = align256(off + (size_t)M * sizeof(int));
    int* Td         = (int*)(ws + off);    off = align256(off + (size_t)nbk * sizeof(int));
    int* Ts         = (int*)(ws + off);    off = align256(off + (size_t)nbk * sizeof(int));
    int* cnt_out    = (int*)(ws + off);    off = align256(off + (size_t)N * sizeof(int));
    int* cnt_in     = (int*)(ws + off);    off = align256(off + (size_t)N * sizeof(int));
    int* row_ptr    = (int*)(ws + off);    off = align256(off + (size_t)(N + 1) * sizeof(int));

    const int pslice = (E + PA_BLOCKS - 1) / PA_BLOCKS;

    // Dual radix-partition CSR build + degree counts (zero device atomics)
    part_hist_kernel<<<PA_BLOCKS, 256, 0, stream>>>(src, dst, hist_d, hist_s, nbk, E, pslice);
    row_scan_kernel<<<2 * nbk, 512, 0, stream>>>(hist_d, hist_s, Td, Ts, nbk);
    part_scatter_kernel<<<PA_BLOCKS, 256, 0, stream>>>(src, dst, hist_d, hist_s, Td, Ts,
                                                       ebuf, sbuf, nbk, E, pslice);
    bucket_csr_kernel<<<nbk, 256, 0, stream>>>(ebuf, sbuf, Td, Ts, csr_src,
                                               cnt_in, cnt_out, row_ptr, nbk, N, E);

    const int gemm_blocks = (N + 63) / 64;
    const int agg_blocks  = (N + 15) / 16;

    // Layer 1: Y = fp16[(X @ W1) * rs_out] ; agg -> d_out (hidden, relu)
    gemm_scale_kernel<128><<<gemm_blocks, 256, 0, stream>>>(x, W1, cnt_out, Y, N);
    aggregate_kernel<true><<<agg_blocks, 256, 0, stream>>>(Y, row_ptr, csr_src, cnt_in, b1, out, N);

    // Layer 2: Y = fp16[(H @ W2) * rs_out] ; agg -> d_out (final)
    gemm_scale_kernel<64><<<gemm_blocks, 256, 0, stream>>>(out, W2, cnt_out, Y, N);
    aggregate_kernel<false><<<agg_blocks, 256, 0, stream>>>(Y, row_ptr, csr_src, cnt_in, b2, out, N);
}